// Round 1
// baseline (307.099 us; speedup 1.0000x reference)
//
#include <hip/hip_runtime.h>
#include <hip/hip_bf16.h>
#include <math.h>

// Problem constants (from reference)
#define BATCH 4
#define N_ANCHORS 211200
#define CHANNELS 256
#define FM_H 200
#define FM_W 176
#define NKP 4096

#define BOXES_ELEMS (BATCH * N_ANCHORS * 7)   // 5,913,600
#define BEV_ELEMS   (BATCH * CHANNELS * NKP)  // 4,194,304

// ---------------------------------------------------------------------------
// Kernel 1: VoxelNet box decode.
// boxes[...,0:2] = P_xy * ||A_wl|| + A_xy
// boxes[...,2]   = P_z * A_h + A_z
// boxes[...,3:6] = exp(P_wlh) * A_wlh
// boxes[...,6]   = P_yaw + A_yaw
// One thread per box (7 floats in from each input, 7 out). Memory-bound.
// ---------------------------------------------------------------------------
__global__ __launch_bounds__(256) void decode_kernel(
    const float* __restrict__ deltas,
    const float* __restrict__ anchors,
    float* __restrict__ out_boxes)
{
    int i = blockIdx.x * blockDim.x + threadIdx.x;
    if (i >= BATCH * N_ANCHORS) return;

    const float* d = deltas  + (size_t)i * 7;
    const float* a = anchors + (size_t)i * 7;
    float*       o = out_boxes + (size_t)i * 7;

    float a0 = a[0], a1 = a[1], a2 = a[2];
    float aw = a[3], al = a[4], ah = a[5], ay = a[6];
    float d0 = d[0], d1 = d[1], d2 = d[2];
    float d3 = d[3], d4 = d[4], d5 = d[5], d6 = d[6];

    float dn = sqrtf(aw * aw + al * al);

    o[0] = d0 * dn + a0;
    o[1] = d1 * dn + a1;
    o[2] = d2 * ah + a2;
    o[3] = expf(d3) * aw;
    o[4] = expf(d4) * al;
    o[5] = expf(d5) * ah;
    o[6] = d6 + ay;
}

// ---------------------------------------------------------------------------
// Kernel 2: BEV bilinear gather.
// Replicates the reference exactly, including the grid flip:
//   ix_idx = clip(kx / 0.4, 0, W-1);  iy_idx = clip((ky+40)/0.4, 0, H-1)
//   nx = 2*ix_idx/(W-2) - 1;          ny = 2*iy_idx/(H-2) - 1
//   (after flip) ix = (ny+1)*0.5*(W-1);  iy = (nx+1)*0.5*(H-1)
// Bilinear taps with zeros-padding valid masks (x0+1 can be 176 -> masked,
// y0 can reach 200 -> masked).
// Thread layout: t -> (b, c, k) with k innermost => coalesced output writes;
// keypoint loads (8B per thread, shared across all 256 c) served by cache.
// ---------------------------------------------------------------------------
__global__ __launch_bounds__(256) void bev_gather_kernel(
    const float* __restrict__ fm,          // [B, C, H, W]
    const float* __restrict__ kp,          // [B, K, 3]
    float* __restrict__ out_bev)           // [B, C, K]
{
    size_t t = (size_t)blockIdx.x * blockDim.x + threadIdx.x;
    if (t >= (size_t)BEV_ELEMS) return;

    int k = (int)(t % NKP);
    int c = (int)((t / NKP) % CHANNELS);
    int b = (int)(t / ((size_t)NKP * CHANNELS));

    const float* kpp = kp + ((size_t)b * NKP + k) * 3;
    float kx = kpp[0];
    float ky = kpp[1];

    // indices = (xy - pixel_offset) / (voxel_size * stride); voxel=0.05, stride=8
    float ix_idx = (kx - 0.0f)   / 0.4f;
    float iy_idx = (ky + 40.0f)  / 0.4f;
    // clip to [0, dims] with dims = [W-1, H-1]
    ix_idx = fminf(fmaxf(ix_idx, 0.0f), (float)(FM_W - 1));
    iy_idx = fminf(fmaxf(iy_idx, 0.0f), (float)(FM_H - 1));
    // normalize with (dims - 1)
    float nx = 2.0f * (ix_idx / (float)(FM_W - 2)) - 1.0f;
    float ny = 2.0f * (iy_idx / (float)(FM_H - 2)) - 1.0f;
    // grid flip: grid[...,0] = ny (used as width coord), grid[...,1] = nx
    float ix = (ny + 1.0f) * 0.5f * (float)(FM_W - 1);
    float iy = (nx + 1.0f) * 0.5f * (float)(FM_H - 1);

    float x0f = floorf(ix);
    float y0f = floorf(iy);
    float wx = ix - x0f;
    float wy = iy - y0f;
    int x0 = (int)x0f;
    int y0 = (int)y0f;
    int x1 = x0 + 1;
    int y1 = y0 + 1;

    // zeros-padding valid masks
    float vx0 = (x0 >= 0 && x0 <= FM_W - 1) ? 1.0f : 0.0f;
    float vx1 = (x1 >= 0 && x1 <= FM_W - 1) ? 1.0f : 0.0f;
    float vy0 = (y0 >= 0 && y0 <= FM_H - 1) ? 1.0f : 0.0f;
    float vy1 = (y1 >= 0 && y1 <= FM_H - 1) ? 1.0f : 0.0f;

    int xc0 = min(max(x0, 0), FM_W - 1);
    int xc1 = min(max(x1, 0), FM_W - 1);
    int yc0 = min(max(y0, 0), FM_H - 1);
    int yc1 = min(max(y1, 0), FM_H - 1);

    const float* plane = fm + ((size_t)b * CHANNELS + c) * (FM_H * FM_W);

    float v00 = plane[yc0 * FM_W + xc0] * (vx0 * vy0);
    float v01 = plane[yc0 * FM_W + xc1] * (vx1 * vy0);
    float v10 = plane[yc1 * FM_W + xc0] * (vx0 * vy1);
    float v11 = plane[yc1 * FM_W + xc1] * (vx1 * vy1);

    float r = v00 * (1.0f - wx) * (1.0f - wy)
            + v01 * wx * (1.0f - wy)
            + v10 * (1.0f - wx) * wy
            + v11 * wx * wy;

    out_bev[t] = r;
}

extern "C" void kernel_launch(void* const* d_in, const int* in_sizes, int n_in,
                              void* d_out, int out_size, void* d_ws, size_t ws_size,
                              hipStream_t stream)
{
    const float* deltas  = (const float*)d_in[0];
    const float* anchors = (const float*)d_in[1];
    const float* fm      = (const float*)d_in[2];
    const float* kp      = (const float*)d_in[3];

    float* out_boxes = (float*)d_out;
    float* out_bev   = (float*)d_out + BOXES_ELEMS;

    {
        int n = BATCH * N_ANCHORS;
        int blocks = (n + 255) / 256;
        decode_kernel<<<blocks, 256, 0, stream>>>(deltas, anchors, out_boxes);
    }
    {
        size_t n = (size_t)BEV_ELEMS;
        int blocks = (int)((n + 255) / 256);
        bev_gather_kernel<<<blocks, 256, 0, stream>>>(fm, kp, out_bev);
    }
}

// Round 2
// 265.480 us; speedup vs baseline: 1.1568x; 1.1568x over previous
//
#include <hip/hip_runtime.h>
#include <hip/hip_bf16.h>
#include <math.h>

// Problem constants (from reference)
#define BATCH 4
#define N_ANCHORS 211200
#define CHANNELS 256
#define FM_H 200
#define FM_W 176
#define NKP 4096
#define PLANE (FM_H * FM_W)                   // 35200 floats = 140800 B (fits 160 KiB LDS)

#define BOXES_ELEMS (BATCH * N_ANCHORS * 7)   // 5,913,600
#define BEV_ELEMS   (BATCH * CHANNELS * NKP)  // 4,194,304

// ---------------------------------------------------------------------------
// Kernel 1: VoxelNet box decode, LDS-staged.
// 1024 boxes (7168 floats = 28 KB per array) per 256-thread block.
// Phase 1: dense float4 global->LDS (deltas + anchors).
// Phase 2: each thread decodes 4 boxes from LDS, writes results in-place
//          over the deltas buffer (same-thread RAW only, no barrier needed).
//          LDS addr stride is 7 dwords; gcd(7,32)=1 -> conflict-free banks.
// Phase 3: dense float4 LDS->global store.
// 844800 boxes / 1024 = 825 blocks exactly.
// ---------------------------------------------------------------------------
#define DEC_BOXES 1024
#define DEC_FLOATS (DEC_BOXES * 7)   // 7168
#define DEC_VEC4   (DEC_FLOATS / 4)  // 1792 float4 = 7 iters of 256 threads

__global__ __launch_bounds__(256) void decode_kernel(
    const float* __restrict__ deltas,
    const float* __restrict__ anchors,
    float* __restrict__ out_boxes)
{
    __shared__ float ldsD[DEC_FLOATS];   // 28672 B
    __shared__ float ldsA[DEC_FLOATS];   // 28672 B  (57344 B total)

    const int tid = threadIdx.x;
    const size_t base = (size_t)blockIdx.x * DEC_FLOATS;   // 28672 B-aligned

    const float4* gd = (const float4*)(deltas  + base);
    const float4* ga = (const float4*)(anchors + base);
    float4* ldd4 = (float4*)ldsD;
    float4* lda4 = (float4*)ldsA;

#pragma unroll
    for (int it = 0; it < 7; ++it) {
        int idx = tid + it * 256;
        ldd4[idx] = gd[idx];
        lda4[idx] = ga[idx];
    }
    __syncthreads();

#pragma unroll
    for (int m = 0; m < 4; ++m) {
        int box = tid + m * 256;
        float* d = ldsD + box * 7;
        float* a = ldsA + box * 7;
        float aw = a[3], al = a[4], ah = a[5];
        float dn = sqrtf(aw * aw + al * al);
        float o0 = d[0] * dn + a[0];
        float o1 = d[1] * dn + a[1];
        float o2 = d[2] * ah + a[2];
        float o3 = expf(d[3]) * aw;
        float o4 = expf(d[4]) * al;
        float o5 = expf(d[5]) * ah;
        float o6 = d[6] + a[6];
        d[0] = o0; d[1] = o1; d[2] = o2; d[3] = o3;
        d[4] = o4; d[5] = o5; d[6] = o6;
    }
    __syncthreads();

    float4* go = (float4*)(out_boxes + base);
#pragma unroll
    for (int it = 0; it < 7; ++it) {
        int idx = tid + it * 256;
        go[idx] = ldd4[idx];
    }
}

// ---------------------------------------------------------------------------
// Kernel 2: BEV bilinear gather, plane-in-LDS.
// One block per (b,c) plane: 1024 blocks, 1024 threads (16 waves, 1 block/CU
// at 140.8 KB LDS). Phase 1 streams the whole 200x176 plane into LDS with
// coalesced float4 loads (each plane line fetched from HBM exactly once ->
// kills the 2.4x over-fetch of the scattered-tap version). Phase 2 does the
// 4 bilinear taps from LDS; coalesced stores.
// Grid math replicates the reference exactly, including the grid flip
// (y-normalized coord re-scaled by W-1 and x-normalized by H-1) and the
// zeros-padding valid masks.
// ---------------------------------------------------------------------------
__global__ __launch_bounds__(1024) void bev_gather_kernel(
    const float* __restrict__ fm,          // [B, C, H, W]
    const float* __restrict__ kp,          // [B, K, 3]
    float* __restrict__ out_bev)           // [B, C, K]
{
    extern __shared__ float plane[];       // PLANE floats = 140800 B

    const int tid = threadIdx.x;
    const int bc  = blockIdx.x;            // b*CHANNELS + c
    const int b   = bc / CHANNELS;

    // Phase 1: plane -> LDS. PLANE/4 = 8800 float4; offset 140800 B is 16B-aligned.
    const float4* gp = (const float4*)(fm + (size_t)bc * PLANE);
    float4* lp = (float4*)plane;
    for (int i = tid; i < PLANE / 4; i += 1024) lp[i] = gp[i];
    __syncthreads();

    const float* kpb  = kp + (size_t)b * NKP * 3;
    float*       outp = out_bev + (size_t)bc * NKP;

#pragma unroll
    for (int m = 0; m < NKP / 1024; ++m) {
        int k = tid + m * 1024;
        float kx = kpb[k * 3 + 0];
        float ky = kpb[k * 3 + 1];

        // indices = (xy - pixel_offset) / (voxel_size * stride); voxel=0.05, stride=8
        float ix_idx = kx / 0.4f;
        float iy_idx = (ky + 40.0f) / 0.4f;
        ix_idx = fminf(fmaxf(ix_idx, 0.0f), (float)(FM_W - 1));
        iy_idx = fminf(fmaxf(iy_idx, 0.0f), (float)(FM_H - 1));
        float nx = 2.0f * (ix_idx / (float)(FM_W - 2)) - 1.0f;
        float ny = 2.0f * (iy_idx / (float)(FM_H - 2)) - 1.0f;
        // grid flip: width coord gets ny, height coord gets nx
        float ix = (ny + 1.0f) * 0.5f * (float)(FM_W - 1);
        float iy = (nx + 1.0f) * 0.5f * (float)(FM_H - 1);

        float x0f = floorf(ix);
        float y0f = floorf(iy);
        float wx = ix - x0f;
        float wy = iy - y0f;
        int x0 = (int)x0f, y0 = (int)y0f;
        int x1 = x0 + 1,   y1 = y0 + 1;

        float vx0 = (x0 >= 0 && x0 <= FM_W - 1) ? 1.0f : 0.0f;
        float vx1 = (x1 >= 0 && x1 <= FM_W - 1) ? 1.0f : 0.0f;
        float vy0 = (y0 >= 0 && y0 <= FM_H - 1) ? 1.0f : 0.0f;
        float vy1 = (y1 >= 0 && y1 <= FM_H - 1) ? 1.0f : 0.0f;

        int xc0 = min(max(x0, 0), FM_W - 1);
        int xc1 = min(max(x1, 0), FM_W - 1);
        int yc0 = min(max(y0, 0), FM_H - 1);
        int yc1 = min(max(y1, 0), FM_H - 1);

        float v00 = plane[yc0 * FM_W + xc0] * (vx0 * vy0);
        float v01 = plane[yc0 * FM_W + xc1] * (vx1 * vy0);
        float v10 = plane[yc1 * FM_W + xc0] * (vx0 * vy1);
        float v11 = plane[yc1 * FM_W + xc1] * (vx1 * vy1);

        float r = v00 * (1.0f - wx) * (1.0f - wy)
                + v01 * wx * (1.0f - wy)
                + v10 * (1.0f - wx) * wy
                + v11 * wx * wy;

        outp[k] = r;
    }
}

extern "C" void kernel_launch(void* const* d_in, const int* in_sizes, int n_in,
                              void* d_out, int out_size, void* d_ws, size_t ws_size,
                              hipStream_t stream)
{
    const float* deltas  = (const float*)d_in[0];
    const float* anchors = (const float*)d_in[1];
    const float* fm      = (const float*)d_in[2];
    const float* kp      = (const float*)d_in[3];

    float* out_boxes = (float*)d_out;
    float* out_bev   = (float*)d_out + BOXES_ELEMS;

    // Allow >64KB dynamic LDS (idempotent; not a stream op, graph-capture safe).
    static bool attr_set = false;
    if (!attr_set) {
        hipFuncSetAttribute((const void*)bev_gather_kernel,
                            hipFuncAttributeMaxDynamicSharedMemorySize,
                            PLANE * (int)sizeof(float));
        attr_set = true;
    }

    {
        int blocks = (BATCH * N_ANCHORS) / DEC_BOXES;   // 825 exactly
        decode_kernel<<<blocks, 256, 0, stream>>>(deltas, anchors, out_boxes);
    }
    {
        int blocks = BATCH * CHANNELS;                   // 1024 planes
        bev_gather_kernel<<<blocks, 1024, PLANE * sizeof(float), stream>>>(fm, kp, out_bev);
    }
}